// Round 1
// baseline (282.720 us; speedup 1.0000x reference)
//
#include <hip/hip_runtime.h>
#include <hip/hip_bf16.h>

#define NB 4
#define NI 40000
#define DI 512
#define NH 128
#define TM 64
#define NT 625          // tiles per batch (625*64 = 40000)
#define LDX 520         // x_lds row stride (bf16 elems), +8 pad
#define LDW 136         // w/h/q lds row stride, +8 pad

typedef __attribute__((ext_vector_type(8))) short bf16x8;
typedef __attribute__((ext_vector_type(4))) float f32x4;

__device__ __forceinline__ ushort f2b(float f) {
    union { float f; unsigned u; } x; x.f = f;
    unsigned r = x.u + 0x7FFFu + ((x.u >> 16) & 1u);
    return (ushort)(r >> 16);
}
__device__ __forceinline__ float b2f(ushort u) {
    union { unsigned u; float f; } x; x.u = ((unsigned)u) << 16;
    return x.f;
}

// ---------------- weight transpose + bf16 convert ----------------
// w1t[j][i] = bf16(W1[i][j])  (128x512), w2t[j][k] = bf16(W2[k][j]) (128x128)
__global__ void k_wt(const float* __restrict__ w1, const float* __restrict__ w2,
                     ushort* __restrict__ w1t, ushort* __restrict__ w2t) {
    int idx = blockIdx.x * 256 + threadIdx.x;
    if (idx < 65536) {
        int j = idx >> 9, i = idx & 511;
        w1t[idx] = f2b(w1[i * 128 + j]);
    } else if (idx < 81920) {
        int r = idx - 65536;
        int j = r >> 7, k = r & 127;
        w2t[r] = f2b(w2[k * 128 + j]);
    }
}

// ---------------- argmax over instances ----------------
__global__ void k_argmax(const float* __restrict__ c, int* __restrict__ topidx) {
    int bo = blockIdx.x;            // 0..7
    int b = bo >> 1, o = bo & 1;
    __shared__ float rv[256];
    __shared__ int   ri[256];
    int tid = threadIdx.x;
    float bv = -3.402823466e38f; int bi = 0x7fffffff;
    for (int n = tid; n < NI; n += 256) {
        float v = c[((size_t)b * NI + n) * 2 + o];
        if (v > bv || (v == bv && n < bi)) { bv = v; bi = n; }
    }
    rv[tid] = bv; ri[tid] = bi;
    __syncthreads();
    for (int s = 128; s > 0; s >>= 1) {
        if (tid < s) {
            if (rv[tid + s] > rv[tid] || (rv[tid + s] == rv[tid] && ri[tid + s] < ri[tid])) {
                rv[tid] = rv[tid + s]; ri[tid] = ri[tid + s];
            }
        }
        __syncthreads();
    }
    if (tid == 0) topidx[bo] = ri[0];
}

// ---------------- q_max MLP (f32, 8 rows total) ----------------
__global__ void k_qmax(const float* __restrict__ feats, const int* __restrict__ topidx,
                       const float* __restrict__ w1, const float* __restrict__ b1,
                       const float* __restrict__ w2, const float* __restrict__ b2,
                       float* __restrict__ qmax) {
    int bo = blockIdx.x;            // 0..7
    int b = bo >> 1;
    __shared__ float xs[DI];
    __shared__ float hs[NH];
    int idx = topidx[bo];
    const float* x = feats + ((size_t)b * NI + idx) * DI;
    for (int i = threadIdx.x; i < DI; i += 128) xs[i] = x[i];
    __syncthreads();
    int j = threadIdx.x;            // 128 threads
    float h = b1[j];
    for (int i = 0; i < DI; ++i) h += xs[i] * w1[i * NH + j];
    h = h > 0.f ? h : 0.f;
    hs[j] = h;
    __syncthreads();
    float q = b2[j];
    for (int k = 0; k < NH; ++k) q += hs[k] * w2[k * NH + j];
    qmax[bo * NH + j] = tanhf(q);
}

// ---------------- main fused kernel ----------------
// per block: 64 instances. MLP via MFMA 16x16x32 bf16, then s = Q.qmax/200,
// e = exp(s), U-partials = sum_n e * x (f32), z-partials = sum_n e.
__global__ __launch_bounds__(512)
void k_main(const float* __restrict__ feats,
            const ushort* __restrict__ w1t, const ushort* __restrict__ w2t,
            const float* __restrict__ b1, const float* __restrict__ b2,
            const float* __restrict__ qmax,
            float* __restrict__ s_ws, float* __restrict__ zp, float* __restrict__ Up) {
    __shared__ ushort x_lds[TM * LDX];     // 66560 B
    __shared__ ushort w_lds[128 * LDW];    // 34816 B
    __shared__ ushort h_lds[TM * LDW];     // 17408 B
    __shared__ ushort q_lds[TM * LDW];     // 17408 B
    __shared__ float  e_lds[TM * 2];
    __shared__ float  qm_lds[2 * NH];

    const int tid = threadIdx.x;
    const int b = blockIdx.x / NT;
    const int t = blockIdx.x % NT;
    const int n0 = t * TM;

    if (tid < 256) qm_lds[tid] = qmax[b * 256 + tid];

    // stage X tile (64x512 f32 -> bf16 LDS)
    const float* xg = feats + ((size_t)(b * NI + n0)) * DI;
    const float4* xg4 = (const float4*)xg;
#pragma unroll
    for (int q = 0; q < 16; ++q) {
        int idx = tid + q * 512;           // float4 index, 0..8191
        int row = idx >> 7;
        int c4  = idx & 127;
        float4 v = xg4[idx];
        ushort4 u;
        u.x = f2b(v.x); u.y = f2b(v.y); u.z = f2b(v.z); u.w = f2b(v.w);
        *(ushort4*)&x_lds[row * LDX + c4 * 4] = u;
    }

    const int wave = tid >> 6;
    const int lane = tid & 63;
    const int wm = wave >> 2;              // 0..1
    const int wn = wave & 3;               // 0..3
    const int lr = lane & 15;
    const int lk = (lane >> 4) * 8;        // k offset within fragment
    const int l4 = (lane >> 4) * 4;        // C/D row offset

    f32x4 acc[2][2] = {};

    // layer 1: X[64,512] @ W1[512,128], K chunks of 128
    for (int c = 0; c < 4; ++c) {
#pragma unroll
        for (int q = 0; q < 4; ++q) {
            int idx = tid + q * 512;       // ushort8 groups (2048)
            int row = idx >> 4;
            int g = idx & 15;
            *(uint4*)&w_lds[row * LDW + g * 8] =
                *(const uint4*)&w1t[row * DI + c * 128 + g * 8];
        }
        __syncthreads();
#pragma unroll
        for (int ks = 0; ks < 4; ++ks) {
            int k = c * 128 + ks * 32;
            bf16x8 a0 = *(const bf16x8*)&x_lds[(wm * 32 +      lr) * LDX + k + lk];
            bf16x8 a1 = *(const bf16x8*)&x_lds[(wm * 32 + 16 + lr) * LDX + k + lk];
            bf16x8 bb0 = *(const bf16x8*)&w_lds[(wn * 32 +      lr) * LDW + ks * 32 + lk];
            bf16x8 bb1 = *(const bf16x8*)&w_lds[(wn * 32 + 16 + lr) * LDW + ks * 32 + lk];
            acc[0][0] = __builtin_amdgcn_mfma_f32_16x16x32_bf16(a0, bb0, acc[0][0], 0, 0, 0);
            acc[0][1] = __builtin_amdgcn_mfma_f32_16x16x32_bf16(a0, bb1, acc[0][1], 0, 0, 0);
            acc[1][0] = __builtin_amdgcn_mfma_f32_16x16x32_bf16(a1, bb0, acc[1][0], 0, 0, 0);
            acc[1][1] = __builtin_amdgcn_mfma_f32_16x16x32_bf16(a1, bb1, acc[1][1], 0, 0, 0);
        }
        __syncthreads();
    }

    // epilogue 1: bias + relu -> h_lds (bf16)
#pragma unroll
    for (int m = 0; m < 2; ++m)
#pragma unroll
        for (int n = 0; n < 2; ++n) {
            int col = wn * 32 + n * 16 + lr;
            float bias = b1[col];
#pragma unroll
            for (int r = 0; r < 4; ++r) {
                int row = wm * 32 + m * 16 + l4 + r;
                float v = acc[m][n][r] + bias;
                h_lds[row * LDW + col] = f2b(v > 0.f ? v : 0.f);
            }
        }
    __syncthreads();

    // layer 2: H[64,128] @ W2[128,128]
#pragma unroll
    for (int q = 0; q < 4; ++q) {
        int idx = tid + q * 512;
        int row = idx >> 4;
        int g = idx & 15;
        *(uint4*)&w_lds[row * LDW + g * 8] = *(const uint4*)&w2t[row * NH + g * 8];
    }
    __syncthreads();

    f32x4 acc2[2][2] = {};
#pragma unroll
    for (int ks = 0; ks < 4; ++ks) {
        int k = ks * 32;
        bf16x8 a0 = *(const bf16x8*)&h_lds[(wm * 32 +      lr) * LDW + k + lk];
        bf16x8 a1 = *(const bf16x8*)&h_lds[(wm * 32 + 16 + lr) * LDW + k + lk];
        bf16x8 bb0 = *(const bf16x8*)&w_lds[(wn * 32 +      lr) * LDW + k + lk];
        bf16x8 bb1 = *(const bf16x8*)&w_lds[(wn * 32 + 16 + lr) * LDW + k + lk];
        acc2[0][0] = __builtin_amdgcn_mfma_f32_16x16x32_bf16(a0, bb0, acc2[0][0], 0, 0, 0);
        acc2[0][1] = __builtin_amdgcn_mfma_f32_16x16x32_bf16(a0, bb1, acc2[0][1], 0, 0, 0);
        acc2[1][0] = __builtin_amdgcn_mfma_f32_16x16x32_bf16(a1, bb0, acc2[1][0], 0, 0, 0);
        acc2[1][1] = __builtin_amdgcn_mfma_f32_16x16x32_bf16(a1, bb1, acc2[1][1], 0, 0, 0);
    }

    // epilogue 2: bias + tanh -> q_lds (bf16)
#pragma unroll
    for (int m = 0; m < 2; ++m)
#pragma unroll
        for (int n = 0; n < 2; ++n) {
            int col = wn * 32 + n * 16 + lr;
            float bias = b2[col];
#pragma unroll
            for (int r = 0; r < 4; ++r) {
                int row = wm * 32 + m * 16 + l4 + r;
                q_lds[row * LDW + col] = f2b(tanhf(acc2[m][n][r] + bias));
            }
        }
    __syncthreads();

    // s phase: 128 tasks (n,o) x 4 threads each (32 k per thread)
    {
        int task = tid >> 2;
        int part = tid & 3;
        int n = task >> 1;
        int o = task & 1;
        float p = 0.f;
#pragma unroll
        for (int g = 0; g < 4; ++g) {
            int k = part * 32 + g * 8;
            uint4 v = *(const uint4*)&q_lds[n * LDW + k];
            const float* qm = &qm_lds[o * NH + k];
            p += b2f((ushort)(v.x & 0xffff)) * qm[0] + b2f((ushort)(v.x >> 16)) * qm[1];
            p += b2f((ushort)(v.y & 0xffff)) * qm[2] + b2f((ushort)(v.y >> 16)) * qm[3];
            p += b2f((ushort)(v.z & 0xffff)) * qm[4] + b2f((ushort)(v.z >> 16)) * qm[5];
            p += b2f((ushort)(v.w & 0xffff)) * qm[6] + b2f((ushort)(v.w >> 16)) * qm[7];
        }
        p += __shfl_xor(p, 1);
        p += __shfl_xor(p, 2);
        if (part == 0) {
            float sv = p / 200.f;      // / sqrt(40000)
            s_ws[((size_t)(b * NI + n0 + n)) * 2 + o] = sv;
            e_lds[n * 2 + o] = expf(sv);
        }
    }
    __syncthreads();

    // U phase: per-d f32 accumulation over 64 instances
    {
        int d = tid;                   // 0..511
        float u0 = 0.f, u1 = 0.f;
#pragma unroll 8
        for (int n = 0; n < TM; ++n) {
            float x = b2f(x_lds[n * LDX + d]);
            u0 += e_lds[n * 2] * x;
            u1 += e_lds[n * 2 + 1] * x;
        }
        size_t base = ((size_t)(b * NT + t) * 2) * DI;
        Up[base + d] = u0;
        Up[base + DI + d] = u1;
        if (tid < 2) {
            float z = 0.f;
            for (int n = 0; n < TM; ++n) z += e_lds[n * 2 + tid];
            zp[(b * NT + t) * 2 + tid] = z;
        }
    }
}

// ---------------- Z reduce ----------------
__global__ void k_zred(const float* __restrict__ zp, float* __restrict__ Zt) {
    int bo = blockIdx.x; int b = bo >> 1, o = bo & 1;
    __shared__ float red[256];
    int tid = threadIdx.x;
    float z = 0.f;
    for (int t = tid; t < NT; t += 256) z += zp[(b * NT + t) * 2 + o];
    red[tid] = z; __syncthreads();
    for (int s = 128; s > 0; s >>= 1) {
        if (tid < s) red[tid] += red[tid + s];
        __syncthreads();
    }
    if (tid == 0) Zt[bo] = red[0];
}

// ---------------- A output ----------------
__global__ void k_A(const float* __restrict__ s_ws, const float* __restrict__ Zt,
                    float* __restrict__ outA) {
    int idx = blockIdx.x * 256 + threadIdx.x;  // 0..319999
    int b = idx / (NI * 2);
    int o = idx & 1;
    outA[idx] = expf(s_ws[idx]) / Zt[b * 2 + o];
}

// ---------------- B output ----------------
__global__ void k_B(const float* __restrict__ Up, const float* __restrict__ Zt,
                    float* __restrict__ outB) {
    int bo = blockIdx.x; int d = threadIdx.x;  // 512
    float u = 0.f;
    for (int t = 0; t < NT; ++t)
        u += Up[((size_t)((bo >> 1) * NT + t) * 2 + (bo & 1)) * DI + d];
    outB[bo * DI + d] = u / Zt[bo];
}

// ---------------- C output ----------------
__global__ void k_C(const float* __restrict__ outB, const float* __restrict__ fcc_w,
                    const float* __restrict__ fcc_b, float* __restrict__ outC) {
    int bo = blockIdx.x; int b = bo >> 1, o = bo & 1;
    __shared__ float red[256];
    int tid = threadIdx.x;
    float acc = 0.f;
    for (int idx = tid; idx < 2 * DI; idx += 256) {
        int i = idx >> 9, d = idx & 511;
        acc += outB[(b * 2 + i) * DI + d] * fcc_w[o * (2 * DI) + i * DI + d];
    }
    red[tid] = acc; __syncthreads();
    for (int s = 128; s > 0; s >>= 1) {
        if (tid < s) red[tid] += red[tid + s];
        __syncthreads();
    }
    if (tid == 0) outC[bo] = red[0] + fcc_b[o];
}

extern "C" void kernel_launch(void* const* d_in, const int* in_sizes, int n_in,
                              void* d_out, int out_size, void* d_ws, size_t ws_size,
                              hipStream_t stream) {
    const float* feats = (const float*)d_in[0];
    const float* c     = (const float*)d_in[1];
    const float* q_w1  = (const float*)d_in[2];
    const float* q_b1  = (const float*)d_in[3];
    const float* q_w2  = (const float*)d_in[4];
    const float* q_b2  = (const float*)d_in[5];
    const float* fcc_w = (const float*)d_in[6];
    const float* fcc_b = (const float*)d_in[7];
    float* out = (float*)d_out;

    // workspace layout (bytes)
    char* w = (char*)d_ws;
    ushort* w1t  = (ushort*)(w);                 // 131072
    ushort* w2t  = (ushort*)(w + 131072);        // 32768
    float* qmaxb = (float*)(w + 163840);         // 4096
    int*   topi  = (int*)(w + 167936);           // 32
    float* Zt    = (float*)(w + 167968);         // 32
    float* s_ws  = (float*)(w + 168000);         // 1280000
    float* zp    = (float*)(w + 1448000);        // 20000
    float* Up    = (float*)(w + 1468000);        // 10240000

    float* outC = out;
    float* outA = out + 8;
    float* outB = out + 8 + NB * NI * 2;

    k_wt<<<320, 256, 0, stream>>>(q_w1, q_w2, w1t, w2t);
    k_argmax<<<8, 256, 0, stream>>>(c, topi);
    k_qmax<<<8, 128, 0, stream>>>(feats, topi, q_w1, q_b1, q_w2, q_b2, qmaxb);
    k_main<<<NB * NT, 512, 0, stream>>>(feats, w1t, w2t, q_b1, q_b2, qmaxb, s_ws, zp, Up);
    k_zred<<<8, 256, 0, stream>>>(zp, Zt);
    k_A<<<NB * NI * 2 / 256, 256, 0, stream>>>(s_ws, Zt, outA);
    k_B<<<8, 512, 0, stream>>>(Up, Zt, outB);
    k_C<<<8, 256, 0, stream>>>(outB, fcc_w, fcc_b, outC);
}

// Round 2
// 204.404 us; speedup vs baseline: 1.3831x; 1.3831x over previous
//
#include <hip/hip_runtime.h>
#include <hip/hip_bf16.h>

#define NB 4
#define NI 40000
#define DI 512
#define NH 128
#define TM 32
#define NT 1250         // tiles per batch (1250*32 = 40000)

typedef __attribute__((ext_vector_type(8))) short bf16x8;
typedef __attribute__((ext_vector_type(4))) float f32x4;

__device__ __forceinline__ ushort f2b(float f) {
    union { float f; unsigned u; } x; x.f = f;
    unsigned r = x.u + 0x7FFFu + ((x.u >> 16) & 1u);
    return (ushort)(r >> 16);
}
__device__ __forceinline__ float b2f(ushort u) {
    union { unsigned u; float f; } x; x.u = ((unsigned)u) << 16;
    return x.f;
}

// ---------------- weight transpose + bf16 convert ----------------
__global__ void k_wt(const float* __restrict__ w1, const float* __restrict__ w2,
                     ushort* __restrict__ w1t, ushort* __restrict__ w2t) {
    int idx = blockIdx.x * 256 + threadIdx.x;
    if (idx < 65536) {
        int j = idx >> 9, i = idx & 511;
        w1t[idx] = f2b(w1[i * 128 + j]);
    } else if (idx < 81920) {
        int r = idx - 65536;
        int j = r >> 7, k = r & 127;
        w2t[r] = f2b(w2[k * 128 + j]);
    }
}

// ---------------- argmax stage 1: 128 blocks (bo*16+ch) ----------------
__global__ void k_am1(const float* __restrict__ c, float* __restrict__ pv, int* __restrict__ pi) {
    int blk = blockIdx.x;
    int bo = blk >> 4, ch = blk & 15;
    int b = bo >> 1, o = bo & 1;
    __shared__ float rv[256];
    __shared__ int   ri[256];
    int tid = threadIdx.x;
    float bv = -3.402823466e38f; int bi = 0x7fffffff;
    for (int n = ch * 2500 + tid; n < (ch + 1) * 2500; n += 256) {
        float v = c[((size_t)b * NI + n) * 2 + o];
        if (v > bv || (v == bv && n < bi)) { bv = v; bi = n; }
    }
    rv[tid] = bv; ri[tid] = bi;
    __syncthreads();
    for (int s = 128; s > 0; s >>= 1) {
        if (tid < s) {
            if (rv[tid + s] > rv[tid] || (rv[tid + s] == rv[tid] && ri[tid + s] < ri[tid])) {
                rv[tid] = rv[tid + s]; ri[tid] = ri[tid + s];
            }
        }
        __syncthreads();
    }
    if (tid == 0) { pv[blk] = rv[0]; pi[blk] = ri[0]; }
}

// ---------------- argmax stage 2: 8 blocks ----------------
__global__ void k_am2(const float* __restrict__ pv, const int* __restrict__ pi,
                      int* __restrict__ topidx) {
    int bo = blockIdx.x;
    if (threadIdx.x == 0) {
        float bv = -3.402823466e38f; int bi = 0x7fffffff;
        for (int ch = 0; ch < 16; ++ch) {
            float v = pv[bo * 16 + ch]; int idx = pi[bo * 16 + ch];
            if (v > bv || (v == bv && idx < bi)) { bv = v; bi = idx; }
        }
        topidx[bo] = bi;
    }
}

// ---------------- q_max MLP (f32, 8 rows, k-split 512 threads) ----------------
__global__ void k_qmax(const float* __restrict__ feats, const int* __restrict__ topidx,
                       const float* __restrict__ w1, const float* __restrict__ b1,
                       const float* __restrict__ w2, const float* __restrict__ b2,
                       float* __restrict__ qmax) {
    int bo = blockIdx.x;
    int b = bo >> 1;
    __shared__ float xs[DI];
    __shared__ float hs[NH];
    int tid = threadIdx.x;               // 512
    const float* x = feats + ((size_t)b * NI + topidx[bo]) * DI;
    if (tid < DI) xs[tid] = x[tid];
    __syncthreads();
    int j = tid >> 2, part = tid & 3;
    float p = 0.f;
    for (int i = part * 128; i < part * 128 + 128; ++i)
        p += xs[i] * w1[i * NH + j];
    p += __shfl_xor(p, 1); p += __shfl_xor(p, 2);
    if (part == 0) { float h = p + b1[j]; hs[j] = h > 0.f ? h : 0.f; }
    __syncthreads();
    p = 0.f;
    for (int i = part * 32; i < part * 32 + 32; ++i)
        p += hs[i] * w2[i * NH + j];
    p += __shfl_xor(p, 1); p += __shfl_xor(p, 2);
    if (part == 0) qmax[bo * NH + j] = tanhf(p + b2[j]);
}

// ---------------- main fused kernel ----------------
// TM=32 instances/block, 256 threads (4 waves, wave=wn quarter of 128 cols).
// LDS 43 KB -> 3 blocks/CU. B-operands read directly from L2-resident w1t/w2t.
__global__ __launch_bounds__(256, 3)
void k_main(const float* __restrict__ feats,
            const ushort* __restrict__ w1t, const ushort* __restrict__ w2t,
            const float* __restrict__ b1, const float* __restrict__ b2,
            const float* __restrict__ qmax,
            float* __restrict__ s_ws, float* __restrict__ zp, float* __restrict__ Up) {
    __shared__ ushort x_lds[TM * 512];    // 32 KB, XOR-swizzled rows (stride 1024 B)
    __shared__ ushort h_lds[TM * 128];    // 8 KB, XOR-swizzled rows (stride 256 B)
    __shared__ float  sp_lds[4][TM][2];   // 1 KB  cross-wave s partials
    __shared__ float  e_lds[TM * 2];
    __shared__ float  qm_lds[2 * NH];

    const int tid = threadIdx.x;
    const int b = blockIdx.x / NT;
    const int t = blockIdx.x % NT;
    const int n0 = t * TM;

    qm_lds[tid] = qmax[b * 256 + tid];

    // stage X tile (32x512 f32 -> bf16 LDS, swizzled)
    const float4* xg4 = (const float4*)(feats + ((size_t)(b * NI + n0)) * DI);
#pragma unroll
    for (int q = 0; q < 16; ++q) {
        int idx = tid + q * 256;          // float4 index 0..4095
        int row = idx >> 7;
        int c4  = idx & 127;
        float4 v = xg4[idx];
        ushort4 u;
        u.x = f2b(v.x); u.y = f2b(v.y); u.z = f2b(v.z); u.w = f2b(v.w);
        int byteoff = (c4 * 8) ^ ((row & 7) << 4);
        *(ushort4*)((char*)x_lds + row * 1024 + byteoff) = u;
    }
    __syncthreads();

    const int wn = tid >> 6;
    const int lane = tid & 63;
    const int lr = lane & 15;
    const int lk = (lane >> 4) * 8;       // k elem offset in fragment
    const int l4 = (lane >> 4) * 4;       // C/D row offset
    const int xsw = (lr & 7) << 4;        // row swizzle (same for row and row+16)

    const char* xrow0 = (const char*)x_lds + lr * 1024;
    const char* xrow1 = (const char*)x_lds + (16 + lr) * 1024;
    const ushort* w1b0 = w1t + (size_t)(wn * 32 + lr) * DI + lk;
    const ushort* w1b1 = w1t + (size_t)(wn * 32 + 16 + lr) * DI + lk;

    // layer 1: X[32,512] @ W1[512,128]
    f32x4 acc[2][2] = {};
#pragma unroll 4
    for (int ks = 0; ks < 16; ++ks) {
        int kb = (ks * 32 + lk) * 2;
        bf16x8 a0 = *(const bf16x8*)(xrow0 + (kb ^ xsw));
        bf16x8 a1 = *(const bf16x8*)(xrow1 + (kb ^ xsw));
        bf16x8 b0 = *(const bf16x8*)(w1b0 + ks * 32);
        bf16x8 b1v = *(const bf16x8*)(w1b1 + ks * 32);
        acc[0][0] = __builtin_amdgcn_mfma_f32_16x16x32_bf16(a0, b0,  acc[0][0], 0, 0, 0);
        acc[0][1] = __builtin_amdgcn_mfma_f32_16x16x32_bf16(a0, b1v, acc[0][1], 0, 0, 0);
        acc[1][0] = __builtin_amdgcn_mfma_f32_16x16x32_bf16(a1, b0,  acc[1][0], 0, 0, 0);
        acc[1][1] = __builtin_amdgcn_mfma_f32_16x16x32_bf16(a1, b1v, acc[1][1], 0, 0, 0);
    }

    // epilogue 1: bias + relu -> h_lds (bf16, swizzled)
#pragma unroll
    for (int m = 0; m < 2; ++m)
#pragma unroll
        for (int n = 0; n < 2; ++n) {
            int col = wn * 32 + n * 16 + lr;
            float bias = b1[col];
#pragma unroll
            for (int r = 0; r < 4; ++r) {
                int row = m * 16 + l4 + r;
                float v = acc[m][n][r] + bias;
                *(ushort*)((char*)h_lds + row * 256 + ((col * 2) ^ ((row & 7) << 4))) =
                    f2b(v > 0.f ? v : 0.f);
            }
        }
    __syncthreads();

    // layer 2: H[32,128] @ W2[128,128]
    f32x4 acc2[2][2] = {};
#pragma unroll
    for (int ks = 0; ks < 4; ++ks) {
        int kb = (ks * 32 + lk) * 2;
        bf16x8 a0 = *(const bf16x8*)((const char*)h_lds + lr * 256 + (kb ^ xsw));
        bf16x8 a1 = *(const bf16x8*)((const char*)h_lds + (16 + lr) * 256 + (kb ^ xsw));
        bf16x8 b0 = *(const bf16x8*)(w2t + (wn * 32 + lr) * NH + ks * 32 + lk);
        bf16x8 b1v = *(const bf16x8*)(w2t + (wn * 32 + 16 + lr) * NH + ks * 32 + lk);
        acc2[0][0] = __builtin_amdgcn_mfma_f32_16x16x32_bf16(a0, b0,  acc2[0][0], 0, 0, 0);
        acc2[0][1] = __builtin_amdgcn_mfma_f32_16x16x32_bf16(a0, b1v, acc2[0][1], 0, 0, 0);
        acc2[1][0] = __builtin_amdgcn_mfma_f32_16x16x32_bf16(a1, b0,  acc2[1][0], 0, 0, 0);
        acc2[1][1] = __builtin_amdgcn_mfma_f32_16x16x32_bf16(a1, b1v, acc2[1][1], 0, 0, 0);
    }

    // epilogue 2: tanh + dot with qmax straight from accumulators
#pragma unroll
    for (int m = 0; m < 2; ++m)
#pragma unroll
        for (int r = 0; r < 4; ++r) {
            float p0 = 0.f, p1 = 0.f;
#pragma unroll
            for (int n = 0; n < 2; ++n) {
                int col = wn * 32 + n * 16 + lr;
                float q = tanhf(acc2[m][n][r] + b2[col]);
                p0 += q * qm_lds[col];
                p1 += q * qm_lds[NH + col];
            }
            p0 += __shfl_xor(p0, 1); p1 += __shfl_xor(p1, 1);
            p0 += __shfl_xor(p0, 2); p1 += __shfl_xor(p1, 2);
            p0 += __shfl_xor(p0, 4); p1 += __shfl_xor(p1, 4);
            p0 += __shfl_xor(p0, 8); p1 += __shfl_xor(p1, 8);
            if (lr == 0) {
                int row = m * 16 + l4 + r;
                sp_lds[wn][row][0] = p0;
                sp_lds[wn][row][1] = p1;
            }
        }
    __syncthreads();

    // s-finish: 64 threads, one (row,o) each; also z partial via in-wave reduce
    if (tid < 64) {
        int row = tid >> 1, o = tid & 1;
        float s = (sp_lds[0][row][o] + sp_lds[1][row][o] +
                   sp_lds[2][row][o] + sp_lds[3][row][o]) * 0.005f;  // /sqrt(40000)
        s_ws[((size_t)(b * NI + n0 + row)) * 2 + o] = s;
        float e = expf(s);
        e_lds[row * 2 + o] = e;
        float z = e;
        z += __shfl_xor(z, 2);  z += __shfl_xor(z, 4);
        z += __shfl_xor(z, 8);  z += __shfl_xor(z, 16);
        z += __shfl_xor(z, 32);
        if (tid < 2) zp[(b * NT + t) * 2 + tid] = z;
    }
    __syncthreads();

    // U phase: each thread owns 2 d-columns, accumulate e-weighted sum over 32 rows
    {
        int bc = tid * 4;                 // byte col (2 ushorts)
        float u00 = 0.f, u01 = 0.f, u10 = 0.f, u11 = 0.f;
#pragma unroll 8
        for (int n = 0; n < TM; ++n) {
            unsigned v = *(const unsigned*)((const char*)x_lds + n * 1024 + (bc ^ ((n & 7) << 4)));
            float x0 = b2f((ushort)(v & 0xffff));
            float x1 = b2f((ushort)(v >> 16));
            float e0 = e_lds[n * 2], e1 = e_lds[n * 2 + 1];
            u00 += e0 * x0; u01 += e0 * x1;
            u10 += e1 * x0; u11 += e1 * x1;
        }
        size_t base = ((size_t)(b * NT + t) * 2) * DI;
        float2 v0; v0.x = u00; v0.y = u01;
        float2 v1; v1.x = u10; v1.y = u11;
        *(float2*)&Up[base + tid * 2] = v0;
        *(float2*)&Up[base + DI + tid * 2] = v1;
    }
}

// ---------------- Z reduce ----------------
__global__ void k_zred(const float* __restrict__ zp, float* __restrict__ Zt) {
    int bo = blockIdx.x; int b = bo >> 1, o = bo & 1;
    __shared__ float red[256];
    int tid = threadIdx.x;
    float z = 0.f;
    for (int t = tid; t < NT; t += 256) z += zp[(b * NT + t) * 2 + o];
    red[tid] = z; __syncthreads();
    for (int s = 128; s > 0; s >>= 1) {
        if (tid < s) red[tid] += red[tid + s];
        __syncthreads();
    }
    if (tid == 0) Zt[bo] = red[0];
}

// ---------------- A output ----------------
__global__ void k_A(const float* __restrict__ s_ws, const float* __restrict__ Zt,
                    float* __restrict__ outA) {
    int idx = blockIdx.x * 256 + threadIdx.x;  // 0..319999
    int b = idx / (NI * 2);
    int o = idx & 1;
    outA[idx] = expf(s_ws[idx]) / Zt[b * 2 + o];
}

// ---------------- B reduce stage 1: 200 blocks ----------------
__global__ void k_B1(const float* __restrict__ Up, float* __restrict__ Up2) {
    int blk = blockIdx.x;                // bo*25 + chunk
    int bo = blk / 25, cch = blk % 25;
    int b = bo >> 1, o = bo & 1;
    int d = threadIdx.x;                 // 512
    float u = 0.f;
    for (int t = cch * 50; t < cch * 50 + 50; ++t)
        u += Up[(((size_t)(b * NT + t)) * 2 + o) * DI + d];
    Up2[(size_t)blk * DI + d] = u;
}

// ---------------- B reduce stage 2: 8 blocks ----------------
__global__ void k_B2(const float* __restrict__ Up2, const float* __restrict__ Zt,
                     float* __restrict__ outB) {
    int bo = blockIdx.x; int d = threadIdx.x;
    float u = 0.f;
    for (int cc = 0; cc < 25; ++cc) u += Up2[(size_t)(bo * 25 + cc) * DI + d];
    outB[bo * DI + d] = u / Zt[bo];
}

// ---------------- C output ----------------
__global__ void k_C(const float* __restrict__ outB, const float* __restrict__ fcc_w,
                    const float* __restrict__ fcc_b, float* __restrict__ outC) {
    int bo = blockIdx.x; int b = bo >> 1, o = bo & 1;
    __shared__ float red[256];
    int tid = threadIdx.x;
    float acc = 0.f;
    for (int idx = tid; idx < 2 * DI; idx += 256) {
        int i = idx >> 9, d = idx & 511;
        acc += outB[(b * 2 + i) * DI + d] * fcc_w[o * (2 * DI) + i * DI + d];
    }
    red[tid] = acc; __syncthreads();
    for (int s = 128; s > 0; s >>= 1) {
        if (tid < s) red[tid] += red[tid + s];
        __syncthreads();
    }
    if (tid == 0) outC[bo] = red[0] + fcc_b[o];
}

extern "C" void kernel_launch(void* const* d_in, const int* in_sizes, int n_in,
                              void* d_out, int out_size, void* d_ws, size_t ws_size,
                              hipStream_t stream) {
    const float* feats = (const float*)d_in[0];
    const float* c     = (const float*)d_in[1];
    const float* q_w1  = (const float*)d_in[2];
    const float* q_b1  = (const float*)d_in[3];
    const float* q_w2  = (const float*)d_in[4];
    const float* q_b2  = (const float*)d_in[5];
    const float* fcc_w = (const float*)d_in[6];
    const float* fcc_b = (const float*)d_in[7];
    float* out = (float*)d_out;

    // workspace layout (bytes)
    char* w = (char*)d_ws;
    ushort* w1t  = (ushort*)(w);                 // 131072
    ushort* w2t  = (ushort*)(w + 131072);        // 32768  -> 163840
    float* qmaxb = (float*)(w + 163840);         // 4096   -> 167936
    int*   topi  = (int*)(w + 167936);           // 32     -> 167968
    float* Zt    = (float*)(w + 167968);         // 32     -> 168000
    float* pv    = (float*)(w + 168000);         // 512    -> 168512
    int*   pi    = (int*)(w + 168512);           // 512    -> 169024
    float* s_ws  = (float*)(w + 169024);         // 1280000 -> 1449024
    float* zp    = (float*)(w + 1449024);        // 40000  -> 1489024
    float* Up2   = (float*)(w + 1489024);        // 409600 -> 1898624
    float* Up    = (float*)(w + 1898624);        // 20480000 -> 22378624

    float* outC = out;
    float* outA = out + 8;
    float* outB = out + 8 + NB * NI * 2;

    k_wt<<<320, 256, 0, stream>>>(q_w1, q_w2, w1t, w2t);
    k_am1<<<128, 256, 0, stream>>>(c, pv, pi);
    k_am2<<<8, 64, 0, stream>>>(pv, pi, topi);
    k_qmax<<<8, 512, 0, stream>>>(feats, topi, q_w1, q_b1, q_w2, q_b2, qmaxb);
    k_main<<<NB * NT, 256, 0, stream>>>(feats, w1t, w2t, q_b1, q_b2, qmaxb, s_ws, zp, Up);
    k_zred<<<8, 256, 0, stream>>>(zp, Zt);
    k_A<<<NB * NI * 2 / 256, 256, 0, stream>>>(s_ws, Zt, outA);
    k_B1<<<200, 512, 0, stream>>>(Up, Up2);
    k_B2<<<8, 512, 0, stream>>>(Up2, Zt, outB);
    k_C<<<8, 256, 0, stream>>>(outB, fcc_w, fcc_b, outC);
}